// Round 1
// baseline (142.600 us; speedup 1.0000x reference)
//
#include <hip/hip_runtime.h>
#include <stdint.h>

#define BATCH 256
#define IDIM  8192
#define ODIM  8192
#define MS    64
#define IC    128
#define OC    128
#define NB    1024

#define TM 64
#define TN 128
#define KSPLIT 2
#define IB_PER (IC / KSPLIT)   // 64 ib-iterations per workgroup

typedef __bf16 bf16x8 __attribute__((ext_vector_type(8)));
typedef float  floatx4 __attribute__((ext_vector_type(4)));

// ---- async global->LDS, 16B per lane (guide §5: width=16 is the m93->m97 2x) ----
__device__ __forceinline__ void async_load16(unsigned short* lds_p, const unsigned short* g_p) {
    __builtin_amdgcn_global_load_lds(
        (const __attribute__((address_space(1))) unsigned int*)g_p,
        (__attribute__((address_space(3))) unsigned int*)lds_p,
        16, 0, 0);
}

// RNE f32 -> bf16 (inputs are finite randoms; no NaN handling needed)
__device__ __forceinline__ unsigned short f32_to_bf16(float f) {
    unsigned int u = __float_as_uint(f);
    u += 0x7FFFu + ((u >> 16) & 1u);
    return (unsigned short)(u >> 16);
}

// ---- kernel 1: x fp32 -> bf16, 8 elems/thread ----
__global__ void k_convert_x(const float* __restrict__ x, unsigned short* __restrict__ xb) {
    int t = blockIdx.x * 256 + threadIdx.x;
    const float4* x4 = (const float4*)x;
    float4 a = x4[2 * t], b = x4[2 * t + 1];
    union { unsigned short s[8]; uint4 v; } u;
    u.s[0] = f32_to_bf16(a.x); u.s[1] = f32_to_bf16(a.y);
    u.s[2] = f32_to_bf16(a.z); u.s[3] = f32_to_bf16(a.w);
    u.s[4] = f32_to_bf16(b.x); u.s[5] = f32_to_bf16(b.y);
    u.s[6] = f32_to_bf16(b.z); u.s[7] = f32_to_bf16(b.w);
    ((uint4*)xb)[t] = u.v;
}

// ---- kernel 2: blocks fp32 [b][r][c] -> bf16 transposed [b][c][r] (LDS tile transpose) ----
__global__ void k_convert_blocks(const float* __restrict__ blocks, unsigned short* __restrict__ bt) {
    __shared__ float tile[MS][MS + 1];   // +1 pad: conflict-free column reads
    int b = blockIdx.x;
    const float4* src4 = (const float4*)(blocks + (size_t)b * MS * MS);
    unsigned short* dst = bt + (size_t)b * MS * MS;
    #pragma unroll
    for (int i = 0; i < 4; ++i) {
        int slot = i * 256 + threadIdx.x;          // 1024 float4 slots
        int r = slot >> 4, c4 = (slot & 15) * 4;
        float4 v = src4[slot];
        tile[r][c4 + 0] = v.x; tile[r][c4 + 1] = v.y;
        tile[r][c4 + 2] = v.z; tile[r][c4 + 3] = v.w;
    }
    __syncthreads();
    #pragma unroll
    for (int i = 0; i < 2; ++i) {
        int slot = i * 256 + threadIdx.x;          // 512 octet slots
        int c = slot >> 3, o = slot & 7;
        union { unsigned short s[8]; uint4 v; } u;
        #pragma unroll
        for (int j = 0; j < 8; ++j) u.s[j] = f32_to_bf16(tile[o * 8 + j][c]);
        *(uint4*)(dst + c * MS + o * 8) = u.v;     // [c][r] contiguous, 16B coalesced
    }
}

// ---- kernel 3: block-gathered GEMM, bf16 MFMA 16x16x32, m97-style staging ----
// grid (64 nt, 4 mt, 2 ks), 256 threads (4 waves). Wave w owns N-cols [w*32, w*32+32).
// LDS XOR swizzle: LDS[row][oct] holds global[row][oct ^ (row&7)] (octet = 8 bf16 = 16B).
__global__ __launch_bounds__(256, 2)
void k_mosaic_gemm(const unsigned short* __restrict__ xb,
                   const unsigned short* __restrict__ bt,
                   const int* __restrict__ parts,
                   float* __restrict__ partial) {
    __shared__ __align__(16) unsigned short a_lds[TM * MS];   // 8 KB  [m][k]
    __shared__ __align__(16) unsigned short b_lds[TN * MS];   // 16 KB [n][k] (B^T rows)

    const int tid  = threadIdx.x;
    const int lane = tid & 63;
    const int wave = tid >> 6;
    const int nt = blockIdx.x;
    const int mt = blockIdx.y;
    const int ks = blockIdx.z;

    const int m0  = mt * TM;
    const int ob0 = nt * (TN / MS);
    const int ib0 = ks * IB_PER;

    const int row  = lane & 15;
    const int quad = lane >> 4;

    // iteration-invariant ds_read element offsets (hoisted into registers)
    int a_off[2][4], b_off[2][2];
    #pragma unroll
    for (int kk = 0; kk < 2; ++kk) {
        int oct = kk * 4 + quad;
        #pragma unroll
        for (int mi = 0; mi < 4; ++mi) {
            int r = mi * 16 + row;
            a_off[kk][mi] = r * MS + ((oct ^ (r & 7)) << 3);
        }
        #pragma unroll
        for (int ni = 0; ni < 2; ++ni) {
            int n = wave * 32 + ni * 16 + row;
            b_off[kk][ni] = n * MS + ((oct ^ (n & 7)) << 3);
        }
    }

    floatx4 acc[4][2];
    #pragma unroll
    for (int mi = 0; mi < 4; ++mi)
        #pragma unroll
        for (int ni = 0; ni < 2; ++ni)
            acc[mi][ni] = (floatx4){0.f, 0.f, 0.f, 0.f};

    for (int ib = ib0; ib < ib0 + IB_PER; ++ib) {
        int p0 = parts[ib * OC + ob0];
        int p1 = parts[ib * OC + ob0 + 1];

        // stage A: 512 x 16B slots; slot -> (m = slot>>3, lds oct = slot&7)
        #pragma unroll
        for (int j = 0; j < 2; ++j) {
            int slot = j * 256 + tid;
            int m = slot >> 3;
            int oct = (slot & 7) ^ (m & 7);    // source octet for swizzled dest
            async_load16(&a_lds[slot * 8],
                         xb + (size_t)(m0 + m) * IDIM + ib * MS + oct * 8);
        }
        // stage B: 1024 x 16B slots; n<64 -> block p0, n>=64 -> p1
        #pragma unroll
        for (int j = 0; j < 4; ++j) {
            int slot = j * 256 + tid;
            int n = slot >> 3;
            int oct = (slot & 7) ^ (n & 7);
            int p = (j < 2) ? p0 : p1;
            async_load16(&b_lds[slot * 8],
                         bt + (size_t)p * (MS * MS) + (n & 63) * MS + oct * 8);
        }
        __syncthreads();   // drains vmcnt(0) then barrier (m97 structure)

        #pragma unroll
        for (int kk = 0; kk < 2; ++kk) {
            bf16x8 af[4], bfr[2];
            #pragma unroll
            for (int mi = 0; mi < 4; ++mi)
                af[mi] = *(const bf16x8*)&a_lds[a_off[kk][mi]];
            #pragma unroll
            for (int ni = 0; ni < 2; ++ni)
                bfr[ni] = *(const bf16x8*)&b_lds[b_off[kk][ni]];
            #pragma unroll
            for (int mi = 0; mi < 4; ++mi)
                #pragma unroll
                for (int ni = 0; ni < 2; ++ni)
                    acc[mi][ni] = __builtin_amdgcn_mfma_f32_16x16x32_bf16(
                        af[mi], bfr[ni], acc[mi][ni], 0, 0, 0);
        }
        __syncthreads();
    }

    // epilogue: C/D layout col = lane&15, row = quad*4 + reg (m89/m91-verified)
    float* out = partial + (size_t)ks * BATCH * ODIM;
    const int cbase = nt * TN + wave * 32;
    #pragma unroll
    for (int mi = 0; mi < 4; ++mi)
        #pragma unroll
        for (int ni = 0; ni < 2; ++ni)
            #pragma unroll
            for (int r = 0; r < 4; ++r) {
                int rowg = m0 + mi * 16 + quad * 4 + r;
                int colg = cbase + ni * 16 + row;
                out[(size_t)rowg * ODIM + colg] = acc[mi][ni][r];
            }
}

// ---- kernel 4: sum 2 K-partials + bias ----
__global__ void k_reduce_bias(const float* __restrict__ partial,
                              const float* __restrict__ bias,
                              float* __restrict__ out) {
    int t = blockIdx.x * 256 + threadIdx.x;          // float4 index over [256,8192]
    const float4* p0 = (const float4*)partial;
    const float4* p1 = (const float4*)(partial + (size_t)BATCH * ODIM);
    const float4* b4 = (const float4*)bias;
    float4 a = p0[t], b = p1[t], c = b4[t & (ODIM / 4 - 1)];
    float4 r;
    r.x = a.x + b.x + c.x; r.y = a.y + b.y + c.y;
    r.z = a.z + b.z + c.z; r.w = a.w + b.w + c.w;
    ((float4*)out)[t] = r;
}

extern "C" void kernel_launch(void* const* d_in, const int* in_sizes, int n_in,
                              void* d_out, int out_size, void* d_ws, size_t ws_size,
                              hipStream_t stream) {
    const float* x      = (const float*)d_in[0];
    const float* blocks = (const float*)d_in[1];
    const float* bias   = (const float*)d_in[2];
    const int*   parts  = (const int*)d_in[3];
    float* out = (float*)d_out;

    char* ws = (char*)d_ws;
    unsigned short* xb      = (unsigned short*)ws;                      // 4 MB
    unsigned short* btively = (unsigned short*)(ws + (4u << 20));       // 8 MB blocks_T
    float*          partial = (float*)(ws + (12u << 20));               // 16 MB

    k_convert_x<<<(BATCH * IDIM) / (256 * 8), 256, 0, stream>>>(x, xb);
    k_convert_blocks<<<NB, 256, 0, stream>>>(blocks, btively);
    k_mosaic_gemm<<<dim3(ODIM / TN, BATCH / TM, KSPLIT), 256, 0, stream>>>(xb, btively, parts, partial);
    k_reduce_bias<<<(BATCH * ODIM) / (256 * 4), 256, 0, stream>>>(partial, bias, out);
}

// Round 2
// 125.518 us; speedup vs baseline: 1.1361x; 1.1361x over previous
//
#include <hip/hip_runtime.h>
#include <stdint.h>

#define BATCH 256
#define IDIM  8192
#define ODIM  8192
#define MS    64
#define IC    128
#define OC    128
#define NB    1024

#define TM 128
#define TN 128
#define KSPLIT 4
#define IB_PER (IC / KSPLIT)   // 32 ib-iterations per workgroup

typedef __bf16 bf16x8 __attribute__((ext_vector_type(8)));
typedef float  floatx4 __attribute__((ext_vector_type(4)));

// ---- async global->LDS, 16B per lane ----
__device__ __forceinline__ void async_load16(unsigned short* lds_p, const unsigned short* g_p) {
    __builtin_amdgcn_global_load_lds(
        (const __attribute__((address_space(1))) unsigned int*)g_p,
        (__attribute__((address_space(3))) unsigned int*)lds_p,
        16, 0, 0);
}

__device__ __forceinline__ unsigned short f32_to_bf16(float f) {
    unsigned int u = __float_as_uint(f);
    u += 0x7FFFu + ((u >> 16) & 1u);
    return (unsigned short)(u >> 16);
}

// ---- kernel 1 (fused): blocks fp32 [b][r][c] -> bf16 [b][c][r]  AND  x fp32 -> bf16 ----
__global__ void k_convert(const float* __restrict__ x, const float* __restrict__ blocks,
                          unsigned short* __restrict__ xb, unsigned short* __restrict__ bt) {
    __shared__ float tile[MS][MS + 1];
    int b = blockIdx.x;
    if (b < NB) {
        const float4* src4 = (const float4*)(blocks + (size_t)b * MS * MS);
        unsigned short* dst = bt + (size_t)b * MS * MS;
        #pragma unroll
        for (int i = 0; i < 4; ++i) {
            int slot = i * 256 + threadIdx.x;
            int r = slot >> 4, c4 = (slot & 15) * 4;
            float4 v = src4[slot];
            tile[r][c4 + 0] = v.x; tile[r][c4 + 1] = v.y;
            tile[r][c4 + 2] = v.z; tile[r][c4 + 3] = v.w;
        }
        __syncthreads();
        #pragma unroll
        for (int i = 0; i < 2; ++i) {
            int slot = i * 256 + threadIdx.x;
            int c = slot >> 3, o = slot & 7;
            union { unsigned short s[8]; uint4 v; } u;
            #pragma unroll
            for (int j = 0; j < 8; ++j) u.s[j] = f32_to_bf16(tile[o * 8 + j][c]);
            *(uint4*)(dst + c * MS + o * 8) = u.v;
        }
    } else {
        int t = (b - NB) * 256 + threadIdx.x;     // 128 blocks cover 256*8192 / 8
        const float4* x4 = (const float4*)x;
        float4 a = x4[2 * t], bb = x4[2 * t + 1];
        union { unsigned short s[8]; uint4 v; } u;
        u.s[0] = f32_to_bf16(a.x);  u.s[1] = f32_to_bf16(a.y);
        u.s[2] = f32_to_bf16(a.z);  u.s[3] = f32_to_bf16(a.w);
        u.s[4] = f32_to_bf16(bb.x); u.s[5] = f32_to_bf16(bb.y);
        u.s[6] = f32_to_bf16(bb.z); u.s[7] = f32_to_bf16(bb.w);
        ((uint4*)xb)[t] = u.v;
    }
}

// ---- kernel 2: block-gathered GEMM, 128x128 tile, 2x2 waves of 64x64, BK=64 ----
// LDS XOR swizzle (R1-verified, 0 bank conflicts): LDS[r][oct] = global[r][oct ^ (r&7)]
__global__ __launch_bounds__(256, 2)
void k_mosaic_gemm(const unsigned short* __restrict__ xb,
                   const unsigned short* __restrict__ bt,
                   const int* __restrict__ parts,
                   float* __restrict__ partial) {
    __shared__ __align__(16) unsigned short a_lds[TM * MS];   // 16 KB [m][k]
    __shared__ __align__(16) unsigned short b_lds[TN * MS];   // 16 KB [n][k]

    const int tid  = threadIdx.x;
    const int lane = tid & 63;
    const int wave = tid >> 6;
    const int wrow = wave >> 1;      // 0..1  (M half)
    const int wcol = wave & 1;       // 0..1  (N half)
    const int nt = blockIdx.x;
    const int mt = blockIdx.y;
    const int ks = blockIdx.z;

    const int m0  = mt * TM;
    const int ob0 = nt * (TN / MS);
    const int ib0 = ks * IB_PER;

    const int row  = lane & 15;
    const int quad = lane >> 4;

    // iteration-invariant ds_read element offsets
    int a_off[2][4], b_off[2][4];
    #pragma unroll
    for (int kk = 0; kk < 2; ++kk) {
        int oct = kk * 4 + quad;
        #pragma unroll
        for (int mi = 0; mi < 4; ++mi) {
            int r = wrow * 64 + mi * 16 + row;
            a_off[kk][mi] = r * MS + ((oct ^ (r & 7)) << 3);
        }
        #pragma unroll
        for (int ni = 0; ni < 4; ++ni) {
            int n = wcol * 64 + ni * 16 + row;
            b_off[kk][ni] = n * MS + ((oct ^ (n & 7)) << 3);
        }
    }

    floatx4 acc[4][4];
    #pragma unroll
    for (int mi = 0; mi < 4; ++mi)
        #pragma unroll
        for (int ni = 0; ni < 4; ++ni)
            acc[mi][ni] = (floatx4){0.f, 0.f, 0.f, 0.f};

    for (int ib = ib0; ib < ib0 + IB_PER; ++ib) {
        int p0 = parts[ib * OC + ob0];
        int p1 = parts[ib * OC + ob0 + 1];

        // stage A: 1024 x 16B slots (128 rows x 8 octets)
        #pragma unroll
        for (int j = 0; j < 4; ++j) {
            int slot = j * 256 + tid;
            int m = slot >> 3;
            int oct = (slot & 7) ^ (m & 7);
            async_load16(&a_lds[slot * 8],
                         xb + (size_t)(m0 + m) * IDIM + ib * MS + oct * 8);
        }
        // stage B: 1024 x 16B slots; n<64 -> p0, n>=64 -> p1
        #pragma unroll
        for (int j = 0; j < 4; ++j) {
            int slot = j * 256 + tid;
            int n = slot >> 3;
            int oct = (slot & 7) ^ (n & 7);
            int p = (j < 2) ? p0 : p1;
            async_load16(&b_lds[slot * 8],
                         bt + (size_t)p * (MS * MS) + (n & 63) * MS + oct * 8);
        }
        __syncthreads();

        #pragma unroll
        for (int kk = 0; kk < 2; ++kk) {
            bf16x8 af[4], bfr[4];
            #pragma unroll
            for (int mi = 0; mi < 4; ++mi)
                af[mi] = *(const bf16x8*)&a_lds[a_off[kk][mi]];
            #pragma unroll
            for (int ni = 0; ni < 4; ++ni)
                bfr[ni] = *(const bf16x8*)&b_lds[b_off[kk][ni]];
            #pragma unroll
            for (int mi = 0; mi < 4; ++mi)
                #pragma unroll
                for (int ni = 0; ni < 4; ++ni)
                    acc[mi][ni] = __builtin_amdgcn_mfma_f32_16x16x32_bf16(
                        af[mi], bfr[ni], acc[mi][ni], 0, 0, 0);
        }
        __syncthreads();
    }

    // epilogue: C/D layout col = lane&15, row = quad*4 + reg
    float* out = partial + (size_t)ks * BATCH * ODIM;
    #pragma unroll
    for (int mi = 0; mi < 4; ++mi)
        #pragma unroll
        for (int ni = 0; ni < 4; ++ni)
            #pragma unroll
            for (int r = 0; r < 4; ++r) {
                int rowg = m0 + wrow * 64 + mi * 16 + quad * 4 + r;
                int colg = nt * TN + wcol * 64 + ni * 16 + row;
                out[(size_t)rowg * ODIM + colg] = acc[mi][ni][r];
            }
}

// ---- kernel 3: sum KSPLIT partials + bias ----
__global__ void k_reduce_bias(const float* __restrict__ partial,
                              const float* __restrict__ bias,
                              float* __restrict__ out) {
    int t = blockIdx.x * 256 + threadIdx.x;          // float4 index over [256,8192]
    const float4* b4 = (const float4*)bias;
    float4 c = b4[t & (ODIM / 4 - 1)];
    float4 r = {c.x, c.y, c.z, c.w};
    #pragma unroll
    for (int k = 0; k < KSPLIT; ++k) {
        const float4* p = (const float4*)(partial + (size_t)k * BATCH * ODIM);
        float4 a = p[t];
        r.x += a.x; r.y += a.y; r.z += a.z; r.w += a.w;
    }
    ((float4*)out)[t] = r;
}

extern "C" void kernel_launch(void* const* d_in, const int* in_sizes, int n_in,
                              void* d_out, int out_size, void* d_ws, size_t ws_size,
                              hipStream_t stream) {
    const float* x      = (const float*)d_in[0];
    const float* blocks = (const float*)d_in[1];
    const float* bias   = (const float*)d_in[2];
    const int*   parts  = (const int*)d_in[3];
    float* out = (float*)d_out;

    char* ws = (char*)d_ws;
    unsigned short* xb      = (unsigned short*)ws;                      // 4 MB
    unsigned short* btb     = (unsigned short*)(ws + (4u << 20));       // 8 MB blocks_T
    float*          partial = (float*)(ws + (12u << 20));               // 32 MB (4 x 8 MB)

    k_convert<<<NB + (BATCH * IDIM) / (256 * 8), 256, 0, stream>>>(x, blocks, xb, btb);
    k_mosaic_gemm<<<dim3(ODIM / TN, BATCH / TM, KSPLIT), 256, 0, stream>>>(xb, btb, parts, partial);
    k_reduce_bias<<<(BATCH * ODIM) / (256 * 4), 256, 0, stream>>>(partial, bias, out);
}